// Round 9
// baseline (120.216 us; speedup 1.0000x reference)
//
#include <hip/hip_runtime.h>
#include <math.h>

typedef _Float16 f16;
typedef _Float16 f16x2 __attribute__((ext_vector_type(2)));
typedef _Float16 f16x4 __attribute__((ext_vector_type(4)));

namespace {
constexpr int B = 4, N = 512, K = 128, C = 256;
constexpr int H8 = 128, W8 = 128, P8 = H8 * W8;
constexpr int H16 = 64, W16 = 64, P16 = H16 * W16;
constexpr int NBG = 32;                 // 32x32 normalized tile grid
constexpr int LBINS = NBG * NBG;        // 1024 bins per batch
constexpr int NBINS = B * LBINS;        // 4096
constexpr int NSAMP = B * K * N;        // 524288
constexpr int CAP = 128;                // slots/bin (mean 64, +8 sigma)
constexpr int WROW = 528;               // padded LDS row bytes (512 + 16)
}

__device__ __forceinline__ float fdot2a(f16x2 a, f16x2 b, float c)
{
#if __has_builtin(__builtin_amdgcn_fdot2)
    return __builtin_amdgcn_fdot2(a, b, c, false);
#else
    return c + (float)a.x * (float)b.x + (float)a.y * (float)b.y;
#endif
}

// 16-lane (DPP row) sum reduction, pure VALU pipe
__device__ __forceinline__ float red16_sum(float x)
{
    int t;
    t = __builtin_amdgcn_update_dpp(0, __float_as_int(x), 0xB1,  0xF, 0xF, true);
    x += __int_as_float(t);
    t = __builtin_amdgcn_update_dpp(0, __float_as_int(x), 0x4E,  0xF, 0xF, true);
    x += __int_as_float(t);
    t = __builtin_amdgcn_update_dpp(0, __float_as_int(x), 0x141, 0xF, 0xF, true);
    x += __int_as_float(t);
    t = __builtin_amdgcn_update_dpp(0, __float_as_int(x), 0x140, 0xF, 0xF, true);
    x += __int_as_float(t);
    return x;
}

__device__ __forceinline__ int band32(float g)
{
    int v = (int)((g + 1.0f) * 0.5f * NBG);
    return min(NBG - 1, max(0, v));
}

// blend 4 taps (two 16B channel segments each) + dual dot, 16-lane reduce
__device__ __forceinline__ void blend_dot(
    const float4* A, const float4* Bv, const float* w, const f16x2* nf,
    float& dot, float& n2)
{
    f16x2 v[8];
    {
        const f16 h = (f16)w[0];
        const f16x2 w0{h, h};
        const f16x2* a0 = reinterpret_cast<const f16x2*>(&A[0]);
        const f16x2* b0 = reinterpret_cast<const f16x2*>(&Bv[0]);
#pragma unroll
        for (int c = 0; c < 4; ++c) { v[c] = w0 * a0[c]; v[c + 4] = w0 * b0[c]; }
    }
#pragma unroll
    for (int t = 1; t < 4; ++t) {
        const f16 h = (f16)w[t];
        const f16x2 wt{h, h};
        const f16x2* at = reinterpret_cast<const f16x2*>(&A[t]);
        const f16x2* bt = reinterpret_cast<const f16x2*>(&Bv[t]);
#pragma unroll
        for (int c = 0; c < 4; ++c) { v[c] += wt * at[c]; v[c + 4] += wt * bt[c]; }
    }
    float d0 = 0, d1 = 0, m0 = 0, m1 = 0;
#pragma unroll
    for (int c = 0; c < 4; ++c) { d0 = fdot2a(nf[c], v[c], d0); m0 = fdot2a(v[c], v[c], m0); }
#pragma unroll
    for (int c = 4; c < 8; ++c) { d1 = fdot2a(nf[c], v[c], d1); m1 = fdot2a(v[c], v[c], m1); }
    dot = red16_sum(d0 + d1);
    n2  = red16_sum(m0 + m1);
}

// fused: [B,C,P] fp32 -> [B,P,C] fp16 for both maps (one dispatch)
__global__ __launch_bounds__(256) void k_transpose2(
    const float* __restrict__ in8, const float* __restrict__ in16,
    f16* __restrict__ o8, f16* __restrict__ o16)
{
    __shared__ float tile[64][65];
    int bx = blockIdx.x;
    const float* in; f16* out; int P;
    if (bx < P8 / 64) { in = in8; out = o8; P = P8; }
    else { bx -= P8 / 64; in = in16; out = o16; P = P16; }
    const int b  = blockIdx.z;
    const int p0 = bx * 64;
    const int c0 = blockIdx.y * 64;
    const int tid = threadIdx.x;
    const int tp = tid & 63, tq = tid >> 6;
    const float* src = in + (size_t)b * C * P;
    f16* dst = out + (size_t)b * P * C;
#pragma unroll
    for (int i = 0; i < 16; ++i) {
        const int cl = tq + i * 4;
        tile[cl][tp] = src[(size_t)(c0 + cl) * P + (p0 + tp)];
    }
    __syncthreads();
#pragma unroll
    for (int i = 0; i < 16; ++i) {
        const int pl = tq + i * 4;
        dst[(size_t)(p0 + pl) * C + (c0 + tp)] = (f16)tile[tp][pl];
    }
}

// l2-normalize node features -> fp16 [B,N,C]; one wave per node
__global__ __launch_bounds__(256) void k_prenorm(
    const float* __restrict__ nodef, f16* __restrict__ nnf)
{
    const int node = blockIdx.x * 4 + (threadIdx.x >> 6);
    const int lane = threadIdx.x & 63;
    const float4 v = *reinterpret_cast<const float4*>(
        nodef + (size_t)node * C + lane * 4);
    float nn = v.x * v.x + v.y * v.y + v.z * v.z + v.w * v.w;
#pragma unroll
    for (int off = 32; off; off >>= 1) nn += __shfl_xor(nn, off);
    const float inv = __frsqrt_rn(fmaxf(nn, 1e-24f));
    f16x4 o;
    o.x = (f16)(v.x * inv); o.y = (f16)(v.y * inv);
    o.z = (f16)(v.z * inv); o.w = (f16)(v.w * inv);
    *reinterpret_cast<f16x4*>(nnf + (size_t)node * C + lane * 4) = o;
}

// single-pass scatter into fixed-capacity bins (global atomic rank;
// 4096 counters x ~128 adds each -> a few us)
__global__ __launch_bounds__(256) void k_scatter(
    const float* __restrict__ coords, unsigned* __restrict__ cursor,
    unsigned* __restrict__ order)
{
    const int sid = blockIdx.x * 256 + threadIdx.x;
    const float gx = coords[(size_t)sid * 2 + 0];
    const float gy = coords[(size_t)sid * 2 + 1];
    const int bin = (sid >> 16) * LBINS + band32(gy) * NBG + band32(gx);
    const unsigned r = atomicAdd(&cursor[bin], 1u);
    if (r < CAP) order[(size_t)bin * CAP + r] = (unsigned)sid;
}

// one block per bin: stage the bin's 6x6 scale-8 tap window in LDS,
// read scale-8 taps via LDS pipe, scale-16 taps + nnf via L1 pipe.
__global__ __launch_bounds__(256) void k_sample(
    const float* __restrict__ nodew,   // [B,N]
    const f16*  __restrict__ nnf,      // [B,N,C] normalized fp16
    const float* __restrict__ rel8,    // [B,P8]
    const float* __restrict__ rel16,   // [B,P16]
    const float* __restrict__ coords,  // [B,K,N,2]
    const f16*  __restrict__ ft8,      // [B,P8,C]
    const f16*  __restrict__ ft16,     // [B,P16,C]
    const unsigned* __restrict__ order,
    float4* __restrict__ sr)           // [B,K,N] {sim8,sim16,rel8,rel16}
{
    // XCD-chunked bin swizzle: contiguous bin ranges per XCD
    const int bin = ((blockIdx.x & 7) * (NBINS / 8)) + (blockIdx.x >> 3);
    const int b = bin >> 10, lb = bin & (LBINS - 1);
    const int by = lb >> 5, bx = lb & 31;
    const int tid = threadIdx.x;
    const int grp = tid >> 4, gl = tid & 15;
    const int y0w = 4 * by - 1, x0w = 4 * bx - 1;

    __shared__ __align__(16) unsigned char lds[36 * WROW];

    const f16* f8b = ft8 + (size_t)b * P8 * C;
    const f16* fqb = ft16 + (size_t)b * P16 * C;
    const float* r8b = rel8 + (size_t)b * P8;
    const float* rqb = rel16 + (size_t)b * P16;
    const unsigned* obin = order + (size_t)bin * CAP;

    // stage 6x6 clamped window (36 rows x 512B, padded to 528B)
    for (int i = tid; i < 36 * 33; i += 256) {
        const int r = i / 33, c = i - r * 33;
        const int wy = r / 6, wx = r - wy * 6;
        const int py = min(max(y0w + wy, 0), H8 - 1);
        const int px = min(max(x0w + wx, 0), W8 - 1);
        uint4 v{0, 0, 0, 0};
        if (c < 32)
            v = *reinterpret_cast<const uint4*>(
                f8b + ((size_t)(py * W8 + px)) * C + c * 8);
        *reinterpret_cast<uint4*>(&lds[r * WROW + c * 16]) = v;
    }
    __syncthreads();

    for (int sub = 0; sub < CAP / 16; ++sub) {
        const unsigned sid = obin[sub * 16 + grp];
        if (sid == 0xFFFFFFFFu) break;   // rank-dense: rest of group's slots empty
        const int n = sid & 511, k = (sid >> 9) & 127;
        const float gx = coords[(size_t)sid * 2 + 0];
        const float gy = coords[(size_t)sid * 2 + 1];

        // nnf: lane gl owns channels [8gl,8gl+8) and [128+8gl,128+8gl+8)
        const f16* np_ = nnf + (size_t)(b * N + n) * C;
        const float4 nr0 = *reinterpret_cast<const float4*>(np_ + gl * 8);
        const float4 nr1 = *reinterpret_cast<const float4*>(np_ + 128 + gl * 8);
        f16x2 nf[8];
        {
            const f16x2* h0 = reinterpret_cast<const f16x2*>(&nr0);
            const f16x2* h1 = reinterpret_cast<const f16x2*>(&nr1);
#pragma unroll
            for (int c = 0; c < 4; ++c) { nf[c] = h0[c]; nf[c + 4] = h1[c]; }
        }

        // ---- scale-16: bilinear + issue global loads early (L1 path) ----
        float wq[4]; int qx0, qx1, qy0, qy1;
        {
            const float ix = ((gx + 1.f) * W16 - 1.f) * 0.5f;
            const float iy = ((gy + 1.f) * H16 - 1.f) * 0.5f;
            const float x0f = floorf(ix), y0f = floorf(iy);
            const int x0 = (int)x0f, y0 = (int)y0f, x1 = x0 + 1, y1 = y0 + 1;
            const float fx1 = ix - x0f, fx0 = 1.f - fx1;
            const float fy1 = iy - y0f, fy0 = 1.f - fy1;
            const bool vx0 = x0 >= 0 && x0 < W16, vx1 = x1 >= 0 && x1 < W16;
            const bool vy0 = y0 >= 0 && y0 < H16, vy1 = y1 >= 0 && y1 < H16;
            wq[0] = vx0 && vy0 ? fx0 * fy0 : 0.f;
            wq[1] = vx1 && vy0 ? fx1 * fy0 : 0.f;
            wq[2] = vx0 && vy1 ? fx0 * fy1 : 0.f;
            wq[3] = vx1 && vy1 ? fx1 * fy1 : 0.f;
            qx0 = min(max(x0, 0), W16 - 1); qx1 = min(max(x1, 0), W16 - 1);
            qy0 = min(max(y0, 0), H16 - 1); qy1 = min(max(y1, 0), H16 - 1);
        }
        const int qp[4] = {qy0 * W16 + qx0, qy0 * W16 + qx1,
                           qy1 * W16 + qx0, qy1 * W16 + qx1};
        float4 ga[4], gb[4];
#pragma unroll
        for (int t = 0; t < 4; ++t) {
            const f16* tp = fqb + (size_t)qp[t] * C;
            ga[t] = *reinterpret_cast<const float4*>(tp + gl * 8);
            gb[t] = *reinterpret_cast<const float4*>(tp + 128 + gl * 8);
        }

        // ---- scale-8: bilinear + LDS reads (DS path) ----
        float wp[4]; int sx0, sx1, sy0, sy1;
        {
            const float ix = ((gx + 1.f) * W8 - 1.f) * 0.5f;
            const float iy = ((gy + 1.f) * H8 - 1.f) * 0.5f;
            const float x0f = floorf(ix), y0f = floorf(iy);
            const int x0 = (int)x0f, y0 = (int)y0f, x1 = x0 + 1, y1 = y0 + 1;
            const float fx1 = ix - x0f, fx0 = 1.f - fx1;
            const float fy1 = iy - y0f, fy0 = 1.f - fy1;
            const bool vx0 = x0 >= 0 && x0 < W8, vx1 = x1 >= 0 && x1 < W8;
            const bool vy0 = y0 >= 0 && y0 < H8, vy1 = y1 >= 0 && y1 < H8;
            wp[0] = vx0 && vy0 ? fx0 * fy0 : 0.f;
            wp[1] = vx1 && vy0 ? fx1 * fy0 : 0.f;
            wp[2] = vx0 && vy1 ? fx0 * fy1 : 0.f;
            wp[3] = vx1 && vy1 ? fx1 * fy1 : 0.f;
            sx0 = min(max(x0, 0), W8 - 1); sx1 = min(max(x1, 0), W8 - 1);
            sy0 = min(max(y0, 0), H8 - 1); sy1 = min(max(y1, 0), H8 - 1);
        }
        const int wxa = min(max(sx0 - x0w, 0), 5), wxb = min(max(sx1 - x0w, 0), 5);
        const int wya = min(max(sy0 - y0w, 0), 5), wyb = min(max(sy1 - y0w, 0), 5);
        const int lr[4] = {wya * 6 + wxa, wya * 6 + wxb,
                           wyb * 6 + wxa, wyb * 6 + wxb};
        float4 la[4], lbv[4];
#pragma unroll
        for (int t = 0; t < 4; ++t) {
            la[t]  = *reinterpret_cast<const float4*>(&lds[lr[t] * WROW + gl * 16]);
            lbv[t] = *reinterpret_cast<const float4*>(&lds[lr[t] * WROW + 256 + gl * 16]);
        }

        float dot8, n28;
        blend_dot(la, lbv, wp, nf, dot8, n28);
        const float sim8 = dot8 * __frsqrt_rn(fmaxf(n28, 1e-24f));
        const float rv8 = wp[0] * r8b[sy0 * W8 + sx0] + wp[1] * r8b[sy0 * W8 + sx1]
                        + wp[2] * r8b[sy1 * W8 + sx0] + wp[3] * r8b[sy1 * W8 + sx1];

        float dotq, n2q;
        blend_dot(ga, gb, wq, nf, dotq, n2q);
        const float simq = dotq * __frsqrt_rn(fmaxf(n2q, 1e-24f));
        const float rvq = wq[0] * rqb[qp[0]] + wq[1] * rqb[qp[1]]
                        + wq[2] * rqb[qp[2]] + wq[3] * rqb[qp[3]];

        if (gl == 0) {
            const float wr = nodew[b * N + n];
            sr[(size_t)(b * K + k) * N + n] =
                make_float4(sim8, simq, wr + rv8, wr + rvq);
        }
    }
}

// per (b,k): softmax over N*S of rel, weighted sum of sim
__global__ __launch_bounds__(256) void k_logits(
    const float4* __restrict__ sr, const float* __restrict__ lscale,
    float* __restrict__ logits)
{
    const int bk = blockIdx.x;
    const int tid = threadIdx.x;
    const int lane = tid & 63, wid = tid >> 6;
    const float4* sp = sr + (size_t)bk * N;
    __shared__ float red0[4], red1[4], red2[4];

    float4 e0 = sp[tid], e1 = sp[tid + 256];
    float m = fmaxf(fmaxf(e0.z, e0.w), fmaxf(e1.z, e1.w));
#pragma unroll
    for (int off = 32; off; off >>= 1) m = fmaxf(m, __shfl_xor(m, off));
    if (lane == 0) red0[wid] = m;
    __syncthreads();
    m = fmaxf(fmaxf(red0[0], red0[1]), fmaxf(red0[2], red0[3]));

    const float a0 = expf(e0.z - m), a1 = expf(e0.w - m);
    const float b0 = expf(e1.z - m), b1 = expf(e1.w - m);
    float se = a0 + a1 + b0 + b1;
    float ss = a0 * e0.x + a1 * e0.y + b0 * e1.x + b1 * e1.y;
#pragma unroll
    for (int off = 32; off; off >>= 1) {
        se += __shfl_xor(se, off);
        ss += __shfl_xor(ss, off);
    }
    if (lane == 0) { red1[wid] = se; red2[wid] = ss; }
    __syncthreads();
    if (tid == 0) {
        const float tse = red1[0] + red1[1] + red1[2] + red1[3];
        const float tss = red2[0] + red2[1] + red2[2] + red2[3];
        logits[bk] = (tss / tse) * expf(lscale[0]);
    }
}

// final softmax over K per b
__global__ __launch_bounds__(64) void k_out(
    const float* __restrict__ logits, float* __restrict__ out)
{
    const int b = blockIdx.x;
    const int lane = threadIdx.x;
    const float v0 = logits[b * K + lane];
    const float v1 = logits[b * K + lane + 64];
    float m = fmaxf(v0, v1);
#pragma unroll
    for (int off = 32; off; off >>= 1) m = fmaxf(m, __shfl_xor(m, off));
    const float e0 = expf(v0 - m), e1 = expf(v1 - m);
    float se = e0 + e1;
#pragma unroll
    for (int off = 32; off; off >>= 1) se += __shfl_xor(se, off);
    out[b * K + lane] = e0 / se;
    out[b * K + lane + 64] = e1 / se;
}

extern "C" void kernel_launch(void* const* d_in, const int* in_sizes, int n_in,
                              void* d_out, int out_size, void* d_ws, size_t ws_size,
                              hipStream_t stream)
{
    const float* nodew  = (const float*)d_in[0];
    const float* nodef  = (const float*)d_in[1];
    const float* rel8   = (const float*)d_in[2];
    const float* feat8  = (const float*)d_in[3];
    const float* rel16  = (const float*)d_in[4];
    const float* feat16 = (const float*)d_in[5];
    const float* coords = (const float*)d_in[6];
    const float* lscale = (const float*)d_in[7];

    char* ws = (char*)d_ws;
    size_t off = 0;
    f16* ft8  = (f16*)(ws + off); off += (size_t)B * P8 * C * 2;     // 33.5 MB
    f16* ft16 = (f16*)(ws + off); off += (size_t)B * P16 * C * 2;    //  8.4 MB
    f16* nnf  = (f16*)(ws + off); off += (size_t)B * N * C * 2;      //  1.0 MB
    float4* sr = (float4*)(ws + off); off += (size_t)NSAMP * 16;     //  8.4 MB
    float* logits = (float*)(ws + off); off += (size_t)B * K * 4;
    unsigned* order  = (unsigned*)(ws + off); off += (size_t)NBINS * CAP * 4; // 2.1 MB
    unsigned* cursor = (unsigned*)(ws + off); off += NBINS * 4;
    float* out = (float*)d_out;

    hipMemsetAsync(order, 0xFF, (size_t)NBINS * CAP * sizeof(unsigned), stream);
    hipMemsetAsync(cursor, 0, NBINS * sizeof(unsigned), stream);

    hipLaunchKernelGGL(k_transpose2, dim3(P8 / 64 + P16 / 64, C / 64, B),
                       dim3(256), 0, stream, feat8, feat16, ft8, ft16);
    hipLaunchKernelGGL(k_prenorm, dim3(B * N / 4), dim3(256), 0, stream,
                       nodef, nnf);
    hipLaunchKernelGGL(k_scatter, dim3(NSAMP / 256), dim3(256), 0, stream,
                       coords, cursor, order);
    hipLaunchKernelGGL(k_sample, dim3(NBINS), dim3(256), 0, stream,
                       nodew, nnf, rel8, rel16, coords, ft8, ft16, order, sr);
    hipLaunchKernelGGL(k_logits, dim3(B * K), dim3(256), 0, stream,
                       sr, lscale, logits);
    hipLaunchKernelGGL(k_out, dim3(B), dim3(64), 0, stream, logits, out);
}

// Round 11
// 94.391 us; speedup vs baseline: 1.2736x; 1.2736x over previous
//
#include <hip/hip_runtime.h>
#include <math.h>

typedef _Float16 f16;
typedef _Float16 f16x2 __attribute__((ext_vector_type(2)));
typedef _Float16 f16x4 __attribute__((ext_vector_type(4)));

namespace {
constexpr int B = 4, N = 512, K = 128, C = 256;
constexpr int H8 = 128, W8 = 128, P8 = H8 * W8;
constexpr int H16 = 64, W16 = 64, P16 = H16 * W16;
constexpr int NBG = 32;                 // 32x32 normalized tile grid
constexpr int LBINS = NBG * NBG;        // 1024 bins per batch
constexpr int NBINS = B * LBINS;        // 4096
constexpr int NSAMP = B * K * N;        // 262144 samples total (K*N=65536/batch)
constexpr int WROW = 528;               // padded LDS row bytes (512 + 16)
constexpr int TBX = P8 / 64 + P16 / 64; // 320 transpose x-blocks
constexpr int NCB = NSAMP / 512 / 16;   // 32 count x-blocks (x16 via y,z)
}

__device__ __forceinline__ float fdot2a(f16x2 a, f16x2 b, float c)
{
#if __has_builtin(__builtin_amdgcn_fdot2)
    return __builtin_amdgcn_fdot2(a, b, c, false);
#else
    return c + (float)a.x * (float)b.x + (float)a.y * (float)b.y;
#endif
}

// 16-lane (DPP row) sum reduction, pure VALU pipe
__device__ __forceinline__ float red16_sum(float x)
{
    int t;
    t = __builtin_amdgcn_update_dpp(0, __float_as_int(x), 0xB1,  0xF, 0xF, true);
    x += __int_as_float(t);
    t = __builtin_amdgcn_update_dpp(0, __float_as_int(x), 0x4E,  0xF, 0xF, true);
    x += __int_as_float(t);
    t = __builtin_amdgcn_update_dpp(0, __float_as_int(x), 0x141, 0xF, 0xF, true);
    x += __int_as_float(t);
    t = __builtin_amdgcn_update_dpp(0, __float_as_int(x), 0x140, 0xF, 0xF, true);
    x += __int_as_float(t);
    return x;
}

__device__ __forceinline__ int band32(float g)
{
    int v = (int)((g + 1.0f) * 0.5f * NBG);
    return min(NBG - 1, max(0, v));
}

// blend 4 taps (two 16B channel segments each) + dual dot, 16-lane reduce
__device__ __forceinline__ void blend_dot(
    const float4* A, const float4* Bv, const float* w, const f16x2* nf,
    float& dot, float& n2)
{
    f16x2 v[8];
    {
        const f16 h = (f16)w[0];
        const f16x2 w0{h, h};
        const f16x2* a0 = reinterpret_cast<const f16x2*>(&A[0]);
        const f16x2* b0 = reinterpret_cast<const f16x2*>(&Bv[0]);
#pragma unroll
        for (int c = 0; c < 4; ++c) { v[c] = w0 * a0[c]; v[c + 4] = w0 * b0[c]; }
    }
#pragma unroll
    for (int t = 1; t < 4; ++t) {
        const f16 h = (f16)w[t];
        const f16x2 wt{h, h};
        const f16x2* at = reinterpret_cast<const f16x2*>(&A[t]);
        const f16x2* bt = reinterpret_cast<const f16x2*>(&Bv[t]);
#pragma unroll
        for (int c = 0; c < 4; ++c) { v[c] += wt * at[c]; v[c + 4] += wt * bt[c]; }
    }
    float d0 = 0, d1 = 0, m0 = 0, m1 = 0;
#pragma unroll
    for (int c = 0; c < 4; ++c) { d0 = fdot2a(nf[c], v[c], d0); m0 = fdot2a(v[c], v[c], m0); }
#pragma unroll
    for (int c = 4; c < 8; ++c) { d1 = fdot2a(nf[c], v[c], d1); m1 = fdot2a(v[c], v[c], m1); }
    dot = red16_sum(d0 + d1);
    n2  = red16_sum(m0 + m1);
}

// fused: transpose both maps fp32->[B,P,C] fp16  ||  LDS-aggregated bin count
__global__ __launch_bounds__(256) void k_prep(
    const float* __restrict__ in8, const float* __restrict__ in16,
    f16* __restrict__ o8, f16* __restrict__ o16,
    const float* __restrict__ coords, unsigned* __restrict__ hist)
{
    __shared__ float tile[64][65];
    const int tid = threadIdx.x;
    int bx = blockIdx.x;

    if (bx >= TBX) {
        // ---- count part: 512 samples per (x,y,z) block; 512 blocks total ----
        unsigned* cnt = reinterpret_cast<unsigned*>(tile);
        const int cblk = (bx - TBX) * 16 + blockIdx.y * 4 + blockIdx.z;
        const int sid0 = cblk * 512;
        const int b = sid0 >> 16;
        for (int i = tid; i < LBINS; i += 256) cnt[i] = 0;
        __syncthreads();
#pragma unroll
        for (int j = 0; j < 2; ++j) {
            const int sid = sid0 + j * 256 + tid;
            const float gx = coords[(size_t)sid * 2 + 0];
            const float gy = coords[(size_t)sid * 2 + 1];
            atomicAdd(&cnt[band32(gy) * NBG + band32(gx)], 1u);
        }
        __syncthreads();
        for (int i = tid; i < LBINS; i += 256)
            if (cnt[i]) atomicAdd(&hist[b * LBINS + i], cnt[i]);
        return;
    }

    // ---- transpose part ----
    const float* in; f16* out; int P;
    if (bx < P8 / 64) { in = in8; out = o8; P = P8; }
    else { bx -= P8 / 64; in = in16; out = o16; P = P16; }
    const int b  = blockIdx.z;
    const int p0 = bx * 64;
    const int c0 = blockIdx.y * 64;
    const int tp = tid & 63, tq = tid >> 6;
    const float* src = in + (size_t)b * C * P;
    f16* dst = out + (size_t)b * P * C;
#pragma unroll
    for (int i = 0; i < 16; ++i) {
        const int cl = tq + i * 4;
        tile[cl][tp] = src[(size_t)(c0 + cl) * P + (p0 + tp)];
    }
    __syncthreads();
#pragma unroll
    for (int i = 0; i < 16; ++i) {
        const int pl = tq + i * 4;
        dst[(size_t)(p0 + pl) * C + (c0 + tp)] = (f16)tile[tp][pl];
    }
}

// exclusive scan of 4096 bin counts -> cursor (mutable) + binofs (stable)
__global__ __launch_bounds__(256) void k_scan(
    const unsigned* __restrict__ hist, unsigned* __restrict__ cursor,
    unsigned* __restrict__ binofs)
{
    __shared__ unsigned sums[256];
    const int t = threadIdx.x;
    unsigned v[16];
    unsigned s = 0;
#pragma unroll
    for (int i = 0; i < 16; ++i) { v[i] = s; s += hist[t * 16 + i]; }
    sums[t] = s;
    __syncthreads();
    for (int off = 1; off < 256; off <<= 1) {
        const unsigned x = (t >= off) ? sums[t - off] : 0u;
        __syncthreads();
        sums[t] += x;
        __syncthreads();
    }
    const unsigned pre = (t == 0) ? 0u : sums[t - 1];
#pragma unroll
    for (int i = 0; i < 16; ++i) {
        cursor[t * 16 + i] = pre + v[i];
        binofs[t * 16 + i] = pre + v[i];
    }
    if (t == 255) binofs[NBINS] = sums[255];
}

// fused: LDS-aggregated dense scatter  ||  node-feature prenorm -> fp16
__global__ __launch_bounds__(256) void k_scatprep(
    const float* __restrict__ coords, unsigned* __restrict__ cursor,
    unsigned* __restrict__ order,
    const float* __restrict__ nodef, f16* __restrict__ nnf)
{
    const int tid = threadIdx.x;
    if (blockIdx.x >= NSAMP / 512) {
        // ---- prenorm part: 4 nodes per block ----
        const int node = (blockIdx.x - NSAMP / 512) * 4 + (tid >> 6);
        const int lane = tid & 63;
        const float4 v = *reinterpret_cast<const float4*>(
            nodef + (size_t)node * C + lane * 4);
        float nn = v.x * v.x + v.y * v.y + v.z * v.z + v.w * v.w;
#pragma unroll
        for (int off = 32; off; off >>= 1) nn += __shfl_xor(nn, off);
        const float inv = __frsqrt_rn(fmaxf(nn, 1e-24f));
        f16x4 o;
        o.x = (f16)(v.x * inv); o.y = (f16)(v.y * inv);
        o.z = (f16)(v.z * inv); o.w = (f16)(v.w * inv);
        *reinterpret_cast<f16x4*>(nnf + (size_t)node * C + lane * 4) = o;
        return;
    }

    __shared__ unsigned cnt[LBINS], base[LBINS];
    const int sid0 = blockIdx.x * 512;
    const int b = sid0 >> 16;
    for (int i = tid; i < LBINS; i += 256) cnt[i] = 0;
    __syncthreads();
    int bl[2];
#pragma unroll
    for (int j = 0; j < 2; ++j) {
        const int sid = sid0 + j * 256 + tid;
        const float gx = coords[(size_t)sid * 2 + 0];
        const float gy = coords[(size_t)sid * 2 + 1];
        bl[j] = band32(gy) * NBG + band32(gx);
        atomicAdd(&cnt[bl[j]], 1u);
    }
    __syncthreads();
    for (int i = tid; i < LBINS; i += 256)
        base[i] = cnt[i] ? atomicAdd(&cursor[b * LBINS + i], cnt[i]) : 0u;
    __syncthreads();
    for (int i = tid; i < LBINS; i += 256) cnt[i] = 0;
    __syncthreads();
#pragma unroll
    for (int j = 0; j < 2; ++j) {
        const int sid = sid0 + j * 256 + tid;
        const unsigned r = base[bl[j]] + atomicAdd(&cnt[bl[j]], 1u);
        order[r] = (unsigned)sid;
    }
}

// one block per bin: stage 6x6 scale-8 window + rel windows in LDS.
// scale-8 taps via DS pipe; scale-16 taps + nnf via L1 pipe.
__global__ __launch_bounds__(256) void k_sample(
    const float* __restrict__ nodew,   // [B,N]
    const f16*  __restrict__ nnf,      // [B,N,C] normalized fp16
    const float* __restrict__ rel8,    // [B,P8]
    const float* __restrict__ rel16,   // [B,P16]
    const float* __restrict__ coords,  // [B,K,N,2]
    const f16*  __restrict__ ft8,      // [B,P8,C]
    const f16*  __restrict__ ft16,     // [B,P16,C]
    const unsigned* __restrict__ order,
    const unsigned* __restrict__ binofs,
    float4* __restrict__ sr)           // [B,K,N] {sim8,sim16,rel8,rel16}
{
    // XCD-chunked bin swizzle: contiguous bin ranges per XCD
    const int bin = ((blockIdx.x & 7) * (NBINS / 8)) + (blockIdx.x >> 3);
    const int b = bin >> 10, lb = bin & (LBINS - 1);
    const int by = lb >> 5, bx = lb & 31;
    const int tid = threadIdx.x;
    const int grp = tid >> 4, gl = tid & 15;
    const int y0w = 4 * by - 1, x0w = 4 * bx - 1;
    const int y0q = 2 * by - 1, x0q = 2 * bx - 1;

    const unsigned s0 = binofs[bin];
    const int cnt = (int)(binofs[bin + 1] - s0);
    if (cnt == 0) return;

    __shared__ __align__(16) unsigned char lds[36 * WROW];
    __shared__ float srel8[36], srel16[16];

    const f16* f8b = ft8 + (size_t)b * P8 * C;
    const f16* fqb = ft16 + (size_t)b * P16 * C;
    const float* r8b = rel8 + (size_t)b * P8;
    const float* rqb = rel16 + (size_t)b * P16;

    // stage 6x6 clamped window (36 rows x 512B, padded to 528B)
    for (int i = tid; i < 36 * 33; i += 256) {
        const int r = i / 33, c = i - r * 33;
        const int wy = r / 6, wx = r - wy * 6;
        const int py = min(max(y0w + wy, 0), H8 - 1);
        const int px = min(max(x0w + wx, 0), W8 - 1);
        uint4 v{0, 0, 0, 0};
        if (c < 32)
            v = *reinterpret_cast<const uint4*>(
                f8b + ((size_t)(py * W8 + px)) * C + c * 8);
        *reinterpret_cast<uint4*>(&lds[r * WROW + c * 16]) = v;
    }
    // stage rel windows (broadcast-read later)
    if (tid < 36) {
        const int wy = tid / 6, wx = tid - wy * 6;
        const int py = min(max(y0w + wy, 0), H8 - 1);
        const int px = min(max(x0w + wx, 0), W8 - 1);
        srel8[tid] = r8b[py * W8 + px];
    } else if (tid < 52) {
        const int i = tid - 36;
        const int wy = i >> 2, wx = i & 3;
        const int py = min(max(y0q + wy, 0), H16 - 1);
        const int px = min(max(x0q + wx, 0), W16 - 1);
        srel16[i] = rqb[py * W16 + px];
    }
    __syncthreads();

    for (int basei = 0; basei < cnt; basei += 16) {
        const int idx = basei + grp;
        const bool active = idx < cnt;
        const unsigned sid = order[s0 + (active ? idx : 0)];
        const int n = sid & 511, k = (sid >> 9) & 127;
        const float gx = coords[(size_t)sid * 2 + 0];
        const float gy = coords[(size_t)sid * 2 + 1];

        // nnf: lane gl owns channels [8gl,8gl+8) and [128+8gl,128+8gl+8)
        const f16* np_ = nnf + (size_t)(b * N + n) * C;
        const float4 nr0 = *reinterpret_cast<const float4*>(np_ + gl * 8);
        const float4 nr1 = *reinterpret_cast<const float4*>(np_ + 128 + gl * 8);
        f16x2 nf[8];
        {
            const f16x2* h0 = reinterpret_cast<const f16x2*>(&nr0);
            const f16x2* h1 = reinterpret_cast<const f16x2*>(&nr1);
#pragma unroll
            for (int c = 0; c < 4; ++c) { nf[c] = h0[c]; nf[c + 4] = h1[c]; }
        }

        // ---- scale-16: bilinear + global loads (L1 path) ----
        float wq[4]; int qx0, qx1, qy0, qy1;
        {
            const float ix = ((gx + 1.f) * W16 - 1.f) * 0.5f;
            const float iy = ((gy + 1.f) * H16 - 1.f) * 0.5f;
            const float x0f = floorf(ix), y0f = floorf(iy);
            const int x0 = (int)x0f, y0 = (int)y0f, x1 = x0 + 1, y1 = y0 + 1;
            const float fx1 = ix - x0f, fx0 = 1.f - fx1;
            const float fy1 = iy - y0f, fy0 = 1.f - fy1;
            const bool vx0 = x0 >= 0 && x0 < W16, vx1 = x1 >= 0 && x1 < W16;
            const bool vy0 = y0 >= 0 && y0 < H16, vy1 = y1 >= 0 && y1 < H16;
            wq[0] = vx0 && vy0 ? fx0 * fy0 : 0.f;
            wq[1] = vx1 && vy0 ? fx1 * fy0 : 0.f;
            wq[2] = vx0 && vy1 ? fx0 * fy1 : 0.f;
            wq[3] = vx1 && vy1 ? fx1 * fy1 : 0.f;
            qx0 = min(max(x0, 0), W16 - 1); qx1 = min(max(x1, 0), W16 - 1);
            qy0 = min(max(y0, 0), H16 - 1); qy1 = min(max(y1, 0), H16 - 1);
        }
        const int qp[4] = {qy0 * W16 + qx0, qy0 * W16 + qx1,
                           qy1 * W16 + qx0, qy1 * W16 + qx1};
        float4 ga[4], gb[4];
#pragma unroll
        for (int t = 0; t < 4; ++t) {
            const f16* tp = fqb + (size_t)qp[t] * C;
            ga[t] = *reinterpret_cast<const float4*>(tp + gl * 8);
            gb[t] = *reinterpret_cast<const float4*>(tp + 128 + gl * 8);
        }

        // ---- scale-8: bilinear + LDS reads (DS path) ----
        float wp[4]; int sx0, sx1, sy0, sy1;
        {
            const float ix = ((gx + 1.f) * W8 - 1.f) * 0.5f;
            const float iy = ((gy + 1.f) * H8 - 1.f) * 0.5f;
            const float x0f = floorf(ix), y0f = floorf(iy);
            const int x0 = (int)x0f, y0 = (int)y0f, x1 = x0 + 1, y1 = y0 + 1;
            const float fx1 = ix - x0f, fx0 = 1.f - fx1;
            const float fy1 = iy - y0f, fy0 = 1.f - fy1;
            const bool vx0 = x0 >= 0 && x0 < W8, vx1 = x1 >= 0 && x1 < W8;
            const bool vy0 = y0 >= 0 && y0 < H8, vy1 = y1 >= 0 && y1 < H8;
            wp[0] = vx0 && vy0 ? fx0 * fy0 : 0.f;
            wp[1] = vx1 && vy0 ? fx1 * fy0 : 0.f;
            wp[2] = vx0 && vy1 ? fx0 * fy1 : 0.f;
            wp[3] = vx1 && vy1 ? fx1 * fy1 : 0.f;
            sx0 = min(max(x0, 0), W8 - 1); sx1 = min(max(x1, 0), W8 - 1);
            sy0 = min(max(y0, 0), H8 - 1); sy1 = min(max(y1, 0), H8 - 1);
        }
        const int wxa = min(max(sx0 - x0w, 0), 5), wxb = min(max(sx1 - x0w, 0), 5);
        const int wya = min(max(sy0 - y0w, 0), 5), wyb = min(max(sy1 - y0w, 0), 5);
        const int lr[4] = {wya * 6 + wxa, wya * 6 + wxb,
                           wyb * 6 + wxa, wyb * 6 + wxb};
        float4 la[4], lbv[4];
#pragma unroll
        for (int t = 0; t < 4; ++t) {
            la[t]  = *reinterpret_cast<const float4*>(&lds[lr[t] * WROW + gl * 16]);
            lbv[t] = *reinterpret_cast<const float4*>(&lds[lr[t] * WROW + 256 + gl * 16]);
        }

        float dot8, n28;
        blend_dot(la, lbv, wp, nf, dot8, n28);
        const float sim8 = dot8 * __frsqrt_rn(fmaxf(n28, 1e-24f));
        const float rv8 = wp[0] * srel8[lr[0]] + wp[1] * srel8[lr[1]]
                        + wp[2] * srel8[lr[2]] + wp[3] * srel8[lr[3]];

        float dotq, n2q;
        blend_dot(ga, gb, wq, nf, dotq, n2q);
        const float simq = dotq * __frsqrt_rn(fmaxf(n2q, 1e-24f));
        const int qwxa = min(max(qx0 - x0q, 0), 3), qwxb = min(max(qx1 - x0q, 0), 3);
        const int qwya = min(max(qy0 - y0q, 0), 3), qwyb = min(max(qy1 - y0q, 0), 3);
        const float rvq = wq[0] * srel16[qwya * 4 + qwxa] + wq[1] * srel16[qwya * 4 + qwxb]
                        + wq[2] * srel16[qwyb * 4 + qwxa] + wq[3] * srel16[qwyb * 4 + qwxb];

        if (active && gl == 0) {
            const float wr = nodew[b * N + n];
            sr[(size_t)(b * K + k) * N + n] =
                make_float4(sim8, simq, wr + rv8, wr + rvq);
        }
    }
}

// per (b,k): softmax over N*S of rel, weighted sum of sim
__global__ __launch_bounds__(256) void k_logits(
    const float4* __restrict__ sr, const float* __restrict__ lscale,
    float* __restrict__ logits)
{
    const int bk = blockIdx.x;
    const int tid = threadIdx.x;
    const int lane = tid & 63, wid = tid >> 6;
    const float4* sp = sr + (size_t)bk * N;
    __shared__ float red0[4], red1[4], red2[4];

    float4 e0 = sp[tid], e1 = sp[tid + 256];
    float m = fmaxf(fmaxf(e0.z, e0.w), fmaxf(e1.z, e1.w));
#pragma unroll
    for (int off = 32; off; off >>= 1) m = fmaxf(m, __shfl_xor(m, off));
    if (lane == 0) red0[wid] = m;
    __syncthreads();
    m = fmaxf(fmaxf(red0[0], red0[1]), fmaxf(red0[2], red0[3]));

    const float a0 = expf(e0.z - m), a1 = expf(e0.w - m);
    const float b0 = expf(e1.z - m), b1 = expf(e1.w - m);
    float se = a0 + a1 + b0 + b1;
    float ss = a0 * e0.x + a1 * e0.y + b0 * e1.x + b1 * e1.y;
#pragma unroll
    for (int off = 32; off; off >>= 1) {
        se += __shfl_xor(se, off);
        ss += __shfl_xor(ss, off);
    }
    if (lane == 0) { red1[wid] = se; red2[wid] = ss; }
    __syncthreads();
    if (tid == 0) {
        const float tse = red1[0] + red1[1] + red1[2] + red1[3];
        const float tss = red2[0] + red2[1] + red2[2] + red2[3];
        logits[bk] = (tss / tse) * expf(lscale[0]);
    }
}

// final softmax over K per b
__global__ __launch_bounds__(64) void k_out(
    const float* __restrict__ logits, float* __restrict__ out)
{
    const int b = blockIdx.x;
    const int lane = threadIdx.x;
    const float v0 = logits[b * K + lane];
    const float v1 = logits[b * K + lane + 64];
    float m = fmaxf(v0, v1);
#pragma unroll
    for (int off = 32; off; off >>= 1) m = fmaxf(m, __shfl_xor(m, off));
    const float e0 = expf(v0 - m), e1 = expf(v1 - m);
    float se = e0 + e1;
#pragma unroll
    for (int off = 32; off; off >>= 1) se += __shfl_xor(se, off);
    out[b * K + lane] = e0 / se;
    out[b * K + lane + 64] = e1 / se;
}

extern "C" void kernel_launch(void* const* d_in, const int* in_sizes, int n_in,
                              void* d_out, int out_size, void* d_ws, size_t ws_size,
                              hipStream_t stream)
{
    const float* nodew  = (const float*)d_in[0];
    const float* nodef  = (const float*)d_in[1];
    const float* rel8   = (const float*)d_in[2];
    const float* feat8  = (const float*)d_in[3];
    const float* rel16  = (const float*)d_in[4];
    const float* feat16 = (const float*)d_in[5];
    const float* coords = (const float*)d_in[6];
    const float* lscale = (const float*)d_in[7];

    char* ws = (char*)d_ws;
    size_t off = 0;
    f16* ft8  = (f16*)(ws + off); off += (size_t)B * P8 * C * 2;     // 33.5 MB
    f16* ft16 = (f16*)(ws + off); off += (size_t)B * P16 * C * 2;    //  8.4 MB
    f16* nnf  = (f16*)(ws + off); off += (size_t)B * N * C * 2;      //  1.0 MB
    float4* sr = (float4*)(ws + off); off += (size_t)NSAMP * 16;     //  4.2 MB
    float* logits = (float*)(ws + off); off += (size_t)B * K * 4;
    unsigned* order  = (unsigned*)(ws + off); off += (size_t)NSAMP * 4; // 1.0 MB
    unsigned* hist   = (unsigned*)(ws + off); off += NBINS * 4;
    unsigned* cursor = (unsigned*)(ws + off); off += NBINS * 4;
    unsigned* binofs = (unsigned*)(ws + off); off += (NBINS + 1) * 4;
    float* out = (float*)d_out;

    hipMemsetAsync(hist, 0, NBINS * sizeof(unsigned), stream);

    hipLaunchKernelGGL(k_prep, dim3(TBX + NCB, C / 64, B), dim3(256), 0, stream,
                       feat8, feat16, ft8, ft16, coords, hist);
    hipLaunchKernelGGL(k_scan, dim3(1), dim3(256), 0, stream,
                       hist, cursor, binofs);
    hipLaunchKernelGGL(k_scatprep, dim3(NSAMP / 512 + B * N / 4), dim3(256), 0,
                       stream, coords, cursor, order, nodef, nnf);
    hipLaunchKernelGGL(k_sample, dim3(NBINS), dim3(256), 0, stream,
                       nodew, nnf, rel8, rel16, coords, ft8, ft16, order,
                       binofs, sr);
    hipLaunchKernelGGL(k_logits, dim3(B * K), dim3(256), 0, stream,
                       sr, lscale, logits);
    hipLaunchKernelGGL(k_out, dim3(B), dim3(64), 0, stream, logits, out);
}